// Round 3
// baseline (1451.332 us; speedup 1.0000x reference)
//
#include <hip/hip_runtime.h>
#include <cstddef>

// ---------------------------------------------------------------------------
// PolyaAKT interaction embedder, MI355X/gfx950.  Inputs fp32, output fp32.
// Control path (logits/GRU) in fp64 VALU for argmax fidelity; value path
// (experts/LN/proj) in bf16 MFMA.  Per-q dedup: q_summary/gru_in/xg/lq and
// expert outputs depend only on q (10000 values), not tokens (32768).
// R3: GRU restructured to LDS-only steady state (1 barrier/step, chunked
// global I/O), inlined fp64 exp poly; qsk LDS->double; smallk 4-way ILP.
// ---------------------------------------------------------------------------

#define NQ 10000
#define TT 32768   // B*S
#define GC 32      // GRU chunk steps

typedef __attribute__((ext_vector_type(8))) short bf16x8;
typedef __attribute__((ext_vector_type(4))) float f32x4;

__device__ double g_qs  [NQ * 256];      // q_summary (relu'd), fp64
__device__ double g_xgq [NQ * 192];      // gru_in_q @ W_ih^T
__device__ double g_xgr [2 * 192];       // (resp@red2 + red_b) @ W_ih^T + b_ih
__device__ double g_xg0 [192];           // start_token @ W_ih^T + b_ih
__device__ double g_lq  [NQ * 4];        // qs @ wgate[0:256]
__device__ double g_m   [TT * 64];       // GRU hidden per token
__device__ int    g_top1[TT];
__device__ unsigned short g_w1t  [4 * 256 * 256];  // bf16 [e][n][k]
__device__ unsigned short g_w2t  [4 * 256 * 256];
__device__ unsigned short g_projt[512 * 256];      // bf16 [n(cor|inc)][k]
__device__ unsigned short g_qf   [NQ * 4 * 256];   // LN'd expert out, bf16

__device__ __forceinline__ float bf2f(unsigned short x) {
  return __uint_as_float(((unsigned)x) << 16);
}
__device__ __forceinline__ unsigned short f2bf(float f) {
  unsigned u = __float_as_uint(f);
  u += 0x7FFFu + ((u >> 16) & 1u);   // RNE
  return (unsigned short)(u >> 16);
}
__device__ __forceinline__ f32x4 mfma16(bf16x8 a, bf16x8 b, f32x4 c) {
  return __builtin_amdgcn_mfma_f32_16x16x32_bf16(a, b, c, 0, 0, 0);
}

// fast fp64 exp: range-reduced, degree-10 poly, rel err ~2e-13 (gate preacts
// are O(0.01); logit gaps are ~1e-8 -- 1e-13 is far below flip threshold).
__device__ __forceinline__ double fexp(double x) {
  const double L2E  = 1.4426950408889634074;
  const double LN2H = 6.93147180369123816490e-01;
  const double LN2L = 1.90821492927058770002e-10;
  double n = rint(x * L2E);
  int ni = (int)n;
  double r = fma(-n, LN2H, x);
  r = fma(-n, LN2L, r);
  double p = 2.7557319223985888e-07;           // 1/10!
  p = fma(p, r, 2.7557319223985893e-06);       // 1/9!
  p = fma(p, r, 2.4801587301587302e-05);       // 1/8!
  p = fma(p, r, 1.9841269841269841e-04);       // 1/7!
  p = fma(p, r, 1.3888888888888889e-03);       // 1/6!
  p = fma(p, r, 8.3333333333333332e-03);       // 1/5!
  p = fma(p, r, 4.1666666666666664e-02);       // 1/4!
  p = fma(p, r, 1.6666666666666666e-01);       // 1/3!
  p = fma(p, r, 0.5);
  p = fma(p, r, 1.0);
  p = fma(p, r, 1.0);
  return ldexp(p, ni);
}

// ---------------------------------------------------------------------------
// prep: bf16 transposed weight tables + fp64 folds (xg_r, xg0).
// ---------------------------------------------------------------------------
__global__ void __launch_bounds__(256) prep_kernel(
    const float* __restrict__ expert_w1, const float* __restrict__ expert_w2,
    const float* __restrict__ proj_cor_w, const float* __restrict__ proj_inc_w,
    const float* __restrict__ resp_table, const float* __restrict__ reducer_w,
    const float* __restrict__ reducer_b,  const float* __restrict__ start_token,
    const float* __restrict__ gru_w_ih,   const float* __restrict__ gru_b_ih)
{
  __shared__ double red2f[128];   // [rr][j]
  const int tid = threadIdx.x;
  if (blockIdx.x == 0) {
    if (tid < 128) {
      const int rr = tid >> 6, j = tid & 63;
      double acc = (double)reducer_b[j];
      for (int k = 0; k < 256; ++k)
        acc += (double)resp_table[rr * 256 + k] *
               (double)reducer_w[(256 + k) * 64 + j];
      red2f[tid] = acc;
    }
    __syncthreads();
    if (tid < 192) {
      const double bih = (double)gru_b_ih[tid];
      double a0 = bih, a1 = bih, a2 = bih;
      for (int j = 0; j < 64; ++j) {
        const double w = (double)gru_w_ih[tid * 64 + j];
        a0 += red2f[j] * w;
        a1 += red2f[64 + j] * w;
        a2 += (double)start_token[j] * w;
      }
      g_xgr[tid] = a0; g_xgr[192 + tid] = a1; g_xg0[tid] = a2;
    }
  }
  const int idx0 = blockIdx.x * 256 + tid;
  const int stride = gridDim.x * 256;
  for (int i = idx0; i < 4 * 256 * 256; i += stride) {
    const int e = i >> 16, rem = i & 65535, n = rem >> 8, k = rem & 255;
    g_w1t[i] = f2bf(expert_w1[e * 65536 + k * 256 + n]);
    g_w2t[i] = f2bf(expert_w2[e * 65536 + k * 256 + n]);
  }
  for (int i = idx0; i < 512 * 256; i += stride) {
    const int n = i >> 8, k = i & 255;
    g_projt[i] = f2bf((n < 256) ? proj_cor_w[k * 256 + n]
                                : proj_inc_w[k * 256 + (n - 256)]);
  }
}

// ---------------------------------------------------------------------------
// qsk: fp64 GEMM  qs[q][n] = relu( emb_row_q(1024) . adapter_w[:,n] + b[n] )
// LDS tiles stored as double (cvt once at stage, not per-FMA).
// ---------------------------------------------------------------------------
__global__ void __launch_bounds__(256) qsk_kernel(
    const float* __restrict__ emb, const float* __restrict__ adapter_w,
    const float* __restrict__ adapter_b)
{
  __shared__ __align__(16) double As[64][33];
  __shared__ __align__(16) double Bs[32][65];
  const int tid = threadIdx.x;
  const int q0 = blockIdx.x * 64;
  const int n0 = blockIdx.y * 64;
  const int ty = tid >> 4, tx = tid & 15;

  double acc[4][4];
#pragma unroll
  for (int i = 0; i < 4; ++i)
#pragma unroll
    for (int j = 0; j < 4; ++j) acc[i][j] = 0.0;

  const int arow = tid >> 2, aks = (tid & 3) * 8;
  const int qa = min(q0 + arow, NQ - 1);
  const int bkk = tid >> 3, bns = (tid & 7) * 8;

  for (int kc = 0; kc < 1024; kc += 32) {
    f32x4 av0 = *(const f32x4*)(emb + (size_t)qa * 1024 + kc + aks);
    f32x4 av1 = *(const f32x4*)(emb + (size_t)qa * 1024 + kc + aks + 4);
    f32x4 bv0 = *(const f32x4*)(adapter_w + (size_t)(kc + bkk) * 256 + n0 + bns);
    f32x4 bv1 = *(const f32x4*)(adapter_w + (size_t)(kc + bkk) * 256 + n0 + bns + 4);
    __syncthreads();
#pragma unroll
    for (int i = 0; i < 4; ++i) { As[arow][aks + i] = (double)av0[i]; As[arow][aks + 4 + i] = (double)av1[i]; }
#pragma unroll
    for (int i = 0; i < 4; ++i) { Bs[bkk][bns + i] = (double)bv0[i]; Bs[bkk][bns + 4 + i] = (double)bv1[i]; }
    __syncthreads();
#pragma unroll 4
    for (int kk = 0; kk < 32; ++kk) {
      double a[4], b[4];
#pragma unroll
      for (int i = 0; i < 4; ++i) a[i] = As[ty * 4 + i][kk];
#pragma unroll
      for (int j = 0; j < 4; ++j) b[j] = Bs[kk][tx * 4 + j];
#pragma unroll
      for (int i = 0; i < 4; ++i)
#pragma unroll
        for (int j = 0; j < 4; ++j) acc[i][j] = fma(a[i], b[j], acc[i][j]);
    }
  }
#pragma unroll
  for (int i = 0; i < 4; ++i) {
    const int qrow = q0 + ty * 4 + i;
    if (qrow < NQ) {
#pragma unroll
      for (int j = 0; j < 4; ++j) {
        const int n = n0 + tx * 4 + j;
        double v = acc[i][j] + (double)adapter_b[n];
        g_qs[(size_t)qrow * 256 + n] = v > 0.0 ? v : 0.0;
      }
    }
  }
}

// ---------------------------------------------------------------------------
// smallk: per q -> gru_in_q(64), xg_q(192), lq(4).  One block per q.
// 4-way accumulator ILP to break fp64 FMA dependence chains.
// ---------------------------------------------------------------------------
__global__ void __launch_bounds__(256) smallk_kernel(
    const float* __restrict__ reducer_w, const float* __restrict__ gru_w_ih,
    const float* __restrict__ wgate_w)
{
  __shared__ double qsr[256];
  __shared__ double ps[4][64];
  __shared__ double gi[64];
  const int tid = threadIdx.x;
  const int qq = blockIdx.x;
  qsr[tid] = g_qs[(size_t)qq * 256 + tid];
  __syncthreads();
  {
    const int j = tid & 63, h = tid >> 6;
    const int k0 = h * 64;
    double a0 = 0.0, a1 = 0.0, a2 = 0.0, a3 = 0.0;
    for (int k = 0; k < 64; k += 4) {
      a0 = fma(qsr[k0 + k + 0], (double)reducer_w[(k0 + k + 0) * 64 + j], a0);
      a1 = fma(qsr[k0 + k + 1], (double)reducer_w[(k0 + k + 1) * 64 + j], a1);
      a2 = fma(qsr[k0 + k + 2], (double)reducer_w[(k0 + k + 2) * 64 + j], a2);
      a3 = fma(qsr[k0 + k + 3], (double)reducer_w[(k0 + k + 3) * 64 + j], a3);
    }
    ps[h][j] = (a0 + a1) + (a2 + a3);
  }
  __syncthreads();
  if (tid < 64) gi[tid] = (ps[0][tid] + ps[1][tid]) + (ps[2][tid] + ps[3][tid]);
  if (tid >= 64 && tid < 68) {
    const int e = tid - 64;
    double a0 = 0.0, a1 = 0.0, a2 = 0.0, a3 = 0.0;
    for (int k = 0; k < 256; k += 4) {
      a0 = fma(qsr[k + 0], (double)wgate_w[(k + 0) * 4 + e], a0);
      a1 = fma(qsr[k + 1], (double)wgate_w[(k + 1) * 4 + e], a1);
      a2 = fma(qsr[k + 2], (double)wgate_w[(k + 2) * 4 + e], a2);
      a3 = fma(qsr[k + 3], (double)wgate_w[(k + 3) * 4 + e], a3);
    }
    g_lq[(size_t)qq * 4 + e] = (a0 + a1) + (a2 + a3);
  }
  __syncthreads();
  if (tid < 192) {
    double a0 = 0.0, a1 = 0.0, a2 = 0.0, a3 = 0.0;
    for (int k = 0; k < 64; k += 4) {
      a0 = fma(gi[k + 0], (double)gru_w_ih[tid * 64 + k + 0], a0);
      a1 = fma(gi[k + 1], (double)gru_w_ih[tid * 64 + k + 1], a1);
      a2 = fma(gi[k + 2], (double)gru_w_ih[tid * 64 + k + 2], a2);
      a3 = fma(gi[k + 3], (double)gru_w_ih[tid * 64 + k + 3], a3);
    }
    g_xgq[(size_t)qq * 192 + tid] = (a0 + a1) + (a2 + a3);
  }
}

// ---------------------------------------------------------------------------
// gru: fp64 scan, LDS-only steady state.  64 blocks x 256 threads.
// Thread (wave w, lane l): owns h-index j = w*16+(l&15), k-slice c = l>>4.
// One barrier per step; x gathered / m flushed in GC-step chunks.
// ---------------------------------------------------------------------------
__global__ void __launch_bounds__(256) gru_kernel(
    const int* __restrict__ q, const int* __restrict__ r,
    const float* __restrict__ whh, const float* __restrict__ bhh)
{
  __shared__ __align__(16) double XL[GC][192];
  __shared__ __align__(16) double MB[GC][64];
  __shared__ __align__(16) double HL[2][64];
  __shared__ int OQ[GC], OR[GC];
  const int tid = threadIdx.x;
  const int w = tid >> 6, lane = tid & 63;
  const int j = w * 16 + (lane & 15);
  const int c = lane >> 4;
  const int b = blockIdx.x;

  double Wr[16], Wz[16], Wn[16];
#pragma unroll
  for (int i = 0; i < 16; ++i) {
    Wr[i] = (double)whh[(0 * 64 + j) * 64 + c * 16 + i];
    Wz[i] = (double)whh[(1 * 64 + j) * 64 + c * 16 + i];
    Wn[i] = (double)whh[(2 * 64 + j) * 64 + c * 16 + i];
  }
  const double br = (double)bhh[j];
  const double bz = (double)bhh[64 + j];
  const double bn = (double)bhh[128 + j];
  if (tid < 64) HL[0][tid] = 0.0;

  int p = 0;
  for (int cc = 0; cc < 512 / GC; ++cc) {
    // token offsets for this chunk (x for step s = gru_in token s-1)
    if (tid < GC) {
      const int s = cc * GC + tid;
      if (s == 0) { OQ[tid] = -1; OR[tid] = 0; }
      else {
        OQ[tid] = q[b * 512 + s - 1] * 192;
        OR[tid] = r[b * 512 + s - 1] * 192;
      }
    }
    __syncthreads();   // OQ/OR visible; previous chunk's XL reads done
    if (tid < 192) {
#pragma unroll 8
      for (int sc = 0; sc < GC; ++sc) {
        const int o = OQ[sc];
        double v;
        if (o < 0) v = g_xg0[tid];
        else       v = g_xgq[(size_t)o + tid] + g_xgr[OR[sc] + tid];
        XL[sc][tid] = v;
      }
    }
    __syncthreads();   // XL visible; drains chunk gathers + prior m flush

    for (int sc = 0; sc < GC; ++sc) {
      double h16[16];
      const double2* hp = (const double2*)&HL[p][c * 16];
#pragma unroll
      for (int i = 0; i < 8; ++i) {
        double2 t2 = hp[i];
        h16[2 * i] = t2.x; h16[2 * i + 1] = t2.y;
      }
      double ar0 = 0.0, ar1 = 0.0, az0 = 0.0, az1 = 0.0, an0 = 0.0, an1 = 0.0;
#pragma unroll
      for (int i = 0; i < 8; ++i) {
        ar0 = fma(Wr[2 * i], h16[2 * i], ar0);
        ar1 = fma(Wr[2 * i + 1], h16[2 * i + 1], ar1);
        az0 = fma(Wz[2 * i], h16[2 * i], az0);
        az1 = fma(Wz[2 * i + 1], h16[2 * i + 1], az1);
        an0 = fma(Wn[2 * i], h16[2 * i], an0);
        an1 = fma(Wn[2 * i + 1], h16[2 * i + 1], an1);
      }
      double hr = ar0 + ar1, hz = az0 + az1, hn = an0 + an1;
      hr += __shfl_xor(hr, 16); hz += __shfl_xor(hz, 16); hn += __shfl_xor(hn, 16);
      hr += __shfl_xor(hr, 32); hz += __shfl_xor(hz, 32); hn += __shfl_xor(hn, 32);
      hr += br; hz += bz; hn += bn;
      const double xr = XL[sc][j], xz = XL[sc][64 + j], xn = XL[sc][128 + j];
      const double rg = 1.0 / (1.0 + fexp(-(xr + hr)));
      const double zg = 1.0 / (1.0 + fexp(-(xz + hz)));
      const double pre = xn + rg * hn;
      const double ng = 1.0 - 2.0 / (fexp(pre + pre) + 1.0);
      const double hprev = HL[p][j];
      const double hnew = fma(zg, hprev - ng, ng);   // (1-z)n + z h
      if (c == 0) { HL[p ^ 1][j] = hnew; MB[sc][j] = hnew; }
      __syncthreads();
      p ^= 1;
    }

    // flush m chunk (coalesced); stores drain at next chunk's barrier
#pragma unroll
    for (int i2 = 0; i2 < GC * 64 / 256; ++i2) {
      const int e = i2 * 256 + tid;
      const int sc = e >> 6, jj = e & 63;
      g_m[((size_t)b * 512 + cc * GC + sc) * 64 + jj] = MB[sc][jj];
    }
  }
}

// ---------------------------------------------------------------------------
// top1: logits = lq[q_t] + m_t @ wgate[256:320] + wgate_b ; first-max argmax.
// ---------------------------------------------------------------------------
__global__ void __launch_bounds__(256) top1_kernel(
    const int* __restrict__ q,
    const float* __restrict__ wgate_w, const float* __restrict__ wgate_b)
{
  __shared__ double w2[256];   // [j][e]
  const int tid = threadIdx.x;
  w2[tid] = (double)wgate_w[1024 + tid];
  __syncthreads();
  const int t = blockIdx.x * 256 + tid;
  const int qv = q[t];
  double l0 = g_lq[(size_t)qv * 4 + 0] + (double)wgate_b[0];
  double l1 = g_lq[(size_t)qv * 4 + 1] + (double)wgate_b[1];
  double l2 = g_lq[(size_t)qv * 4 + 2] + (double)wgate_b[2];
  double l3 = g_lq[(size_t)qv * 4 + 3] + (double)wgate_b[3];
  const double* mr = g_m + (size_t)t * 64;
  for (int jj = 0; jj < 64; ++jj) {
    const double mv = mr[jj];
    l0 = fma(mv, w2[jj * 4 + 0], l0);
    l1 = fma(mv, w2[jj * 4 + 1], l1);
    l2 = fma(mv, w2[jj * 4 + 2], l2);
    l3 = fma(mv, w2[jj * 4 + 3], l3);
  }
  int bi = 0; double bvv = l0;
  if (l1 > bvv) { bvv = l1; bi = 1; }
  if (l2 > bvv) { bvv = l2; bi = 2; }
  if (l3 > bvv) { bvv = l3; bi = 3; }
  g_top1[t] = bi;
}

// ---------------------------------------------------------------------------
// kernelE: per 32 q-values: stage emb rows as bf16; for each expert e:
// h1=relu(qr_e@W1+b1) -> out=h1@W2+b2 -> LN -> qf[q][e] bf16.
// ---------------------------------------------------------------------------
__global__ void __launch_bounds__(128) kernelE(
    const float* __restrict__ emb,
    const float* __restrict__ b1, const float* __restrict__ b2,
    const float* __restrict__ lng, const float* __restrict__ lnb)
{
  __shared__ __align__(16) unsigned short QR[32 * 1032];
  __shared__ __align__(16) unsigned short H1[32 * 264];
  __shared__ __align__(16) unsigned short EO[32 * 264];
  const int tid = threadIdx.x;
  const int t0 = blockIdx.x * 32;
  const int w = tid >> 6;
  const int lane = tid & 63;
  const int l15 = lane & 15;
  const int quad = lane >> 4;

  // stage 32 emb rows (fp32 -> bf16)
  for (int c = 0; c < 64; ++c) {
    const int idx = c * 128 + tid;           // float4 index: 8192 total
    const int row = idx >> 8, col4 = idx & 255;
    const int qv = min(t0 + row, NQ - 1);
    f32x4 v = *(const f32x4*)(emb + (size_t)qv * 1024 + col4 * 4);
    unsigned a = ((unsigned)f2bf(v[1]) << 16) | f2bf(v[0]);
    unsigned bb = ((unsigned)f2bf(v[3]) << 16) | f2bf(v[2]);
    *(uint2*)&QR[row * 1032 + col4 * 4] = make_uint2(a, bb);
  }
  __syncthreads();

  const f32x4 z4 = {0.f, 0.f, 0.f, 0.f};
  const int n0 = w * 128;

  for (int e = 0; e < 4; ++e) {
    // ---- layer 1 ----
    f32x4 acc[2][8];
#pragma unroll
    for (int a = 0; a < 2; ++a)
#pragma unroll
      for (int bq = 0; bq < 8; ++bq) acc[a][bq] = z4;
#pragma unroll
    for (int ks = 0; ks < 8; ++ks) {
      const int koff = e * 256 + ks * 32 + quad * 8;
      bf16x8 a0 = *(const bf16x8*)&QR[l15 * 1032 + koff];
      bf16x8 a1 = *(const bf16x8*)&QR[(16 + l15) * 1032 + koff];
      const int kb = ks * 32 + quad * 8;
#pragma unroll
      for (int nt = 0; nt < 8; ++nt) {
        bf16x8 bbv = *(const bf16x8*)(g_w1t + (size_t)e * 65536 +
                                      (size_t)(n0 + nt * 16 + l15) * 256 + kb);
        acc[0][nt] = mfma16(a0, bbv, acc[0][nt]);
        acc[1][nt] = mfma16(a1, bbv, acc[1][nt]);
      }
    }
#pragma unroll
    for (int nt = 0; nt < 8; ++nt) {
      const int n = n0 + nt * 16 + l15;
      const float b1v = b1[e * 256 + n];
#pragma unroll
      for (int mt = 0; mt < 2; ++mt)
#pragma unroll
        for (int rg = 0; rg < 4; ++rg) {
          const int m = mt * 16 + quad * 4 + rg;
          H1[m * 264 + n] = f2bf(fmaxf(acc[mt][nt][rg] + b1v, 0.f));
        }
    }
    __syncthreads();
    // ---- layer 2 ----
    f32x4 acc2[2][8];
#pragma unroll
    for (int a = 0; a < 2; ++a)
#pragma unroll
      for (int bq = 0; bq < 8; ++bq) acc2[a][bq] = z4;
#pragma unroll
    for (int ks = 0; ks < 8; ++ks) {
      const int koff = ks * 32 + quad * 8;
      bf16x8 a0 = *(const bf16x8*)&H1[l15 * 264 + koff];
      bf16x8 a1 = *(const bf16x8*)&H1[(16 + l15) * 264 + koff];
#pragma unroll
      for (int nt = 0; nt < 8; ++nt) {
        bf16x8 bbv = *(const bf16x8*)(g_w2t + (size_t)e * 65536 +
                                      (size_t)(n0 + nt * 16 + l15) * 256 + koff);
        acc2[0][nt] = mfma16(a0, bbv, acc2[0][nt]);
        acc2[1][nt] = mfma16(a1, bbv, acc2[1][nt]);
      }
    }
#pragma unroll
    for (int nt = 0; nt < 8; ++nt) {
      const int n = n0 + nt * 16 + l15;
      const float b2v = b2[e * 256 + n];
#pragma unroll
      for (int mt = 0; mt < 2; ++mt)
#pragma unroll
        for (int rg = 0; rg < 4; ++rg) {
          const int m = mt * 16 + quad * 4 + rg;
          EO[m * 264 + n] = f2bf(acc2[mt][nt][rg] + b2v);
        }
    }
    __syncthreads();
    // ---- LayerNorm -> qf[qv][e] (4 threads per row) ----
    {
      const int m = tid >> 2;
      const int sub = tid & 3;
      float sx = 0.f, sxx = 0.f;
#pragma unroll
      for (int i = 0; i < 8; ++i) {
        bf16x8 v = *(const bf16x8*)&EO[m * 264 + sub * 64 + i * 8];
#pragma unroll
        for (int c = 0; c < 8; ++c) {
          const float f = bf2f((unsigned short)v[c]);
          sx += f; sxx += f * f;
        }
      }
      sx += __shfl_xor(sx, 1); sxx += __shfl_xor(sxx, 1);
      sx += __shfl_xor(sx, 2); sxx += __shfl_xor(sxx, 2);
      const float mu = sx * (1.f / 256.f);
      const float var = sxx * (1.f / 256.f) - mu * mu;
      const float inv = 1.f / sqrtf(var + 1e-5f);
      if (t0 + m < NQ) {
        const size_t base = ((size_t)(t0 + m) * 4 + e) * 256;
#pragma unroll
        for (int i = 0; i < 8; ++i) {
          const int dbase = sub * 64 + i * 8;
          bf16x8 v = *(const bf16x8*)&EO[m * 264 + dbase];
          bf16x8 ov;
#pragma unroll
          for (int c = 0; c < 8; ++c) {
            const int d = dbase + c;
            const float f = bf2f((unsigned short)v[c]);
            ov[c] = (short)f2bf(lng[d] * (f - mu) * inv + lnb[d]);
          }
          *(bf16x8*)(g_qf + base + dbase) = ov;
        }
      }
    }
    __syncthreads();
  }
}

// ---------------------------------------------------------------------------
// kernelF: per 32 tokens: gather qf[q_t][top1_t] -> q_fused out (fp32) and
// LDS; proj (cor|inc) bf16 MFMA; qa_fused by r.  out is float*.
// ---------------------------------------------------------------------------
__global__ void __launch_bounds__(128) kernelF(
    const int* __restrict__ q, const int* __restrict__ r,
    const float* __restrict__ pcb, const float* __restrict__ pib,
    float* __restrict__ out)
{
  __shared__ __align__(16) unsigned short QF[32 * 264];
  __shared__ int rv_l[32];
  const int tid = threadIdx.x;
  const int t0 = blockIdx.x * 32;
  const int w = tid >> 6;
  const int lane = tid & 63;
  const int l15 = lane & 15;
  const int quad = lane >> 4;
  if (tid < 32) rv_l[tid] = r[t0 + tid];
  __syncthreads();

  {
    const int m = tid >> 2;
    const size_t row = ((size_t)q[t0 + m] * 4 + g_top1[t0 + m]) * 256;
#pragma unroll
    for (int i = 0; i < 8; ++i) {
      const int dbase = (tid & 3) * 64 + i * 8;
      bf16x8 v = *(const bf16x8*)(g_qf + row + dbase);
      *(bf16x8*)&QF[m * 264 + dbase] = v;
      f32x4 f0, f1;
#pragma unroll
      for (int c = 0; c < 4; ++c) f0[c] = bf2f((unsigned short)v[c]);
#pragma unroll
      for (int c = 0; c < 4; ++c) f1[c] = bf2f((unsigned short)v[4 + c]);
      *(f32x4*)(out + (size_t)(t0 + m) * 256 + dbase) = f0;
      *(f32x4*)(out + (size_t)(t0 + m) * 256 + dbase + 4) = f1;
    }
  }
  __syncthreads();

  const f32x4 z4 = {0.f, 0.f, 0.f, 0.f};
  const int n0 = w * 128;
  for (int ph = 0; ph < 2; ++ph) {
    f32x4 acc[2][8];
#pragma unroll
    for (int a = 0; a < 2; ++a)
#pragma unroll
      for (int bq = 0; bq < 8; ++bq) acc[a][bq] = z4;
#pragma unroll
    for (int ks = 0; ks < 8; ++ks) {
      const int koff = ks * 32 + quad * 8;
      bf16x8 a0 = *(const bf16x8*)&QF[l15 * 264 + koff];
      bf16x8 a1 = *(const bf16x8*)&QF[(16 + l15) * 264 + koff];
#pragma unroll
      for (int nt = 0; nt < 8; ++nt) {
        bf16x8 bbv = *(const bf16x8*)(g_projt +
            (size_t)(ph * 256 + n0 + nt * 16 + l15) * 256 + koff);
        acc[0][nt] = mfma16(a0, bbv, acc[0][nt]);
        acc[1][nt] = mfma16(a1, bbv, acc[1][nt]);
      }
    }
    const float* pbb = ph ? pib : pcb;
    const int want = ph ? 0 : 1;
#pragma unroll
    for (int nt = 0; nt < 8; ++nt) {
      const int n = n0 + nt * 16 + l15;
      const float pbv = pbb[n];
#pragma unroll
      for (int mt = 0; mt < 2; ++mt)
#pragma unroll
        for (int rg = 0; rg < 4; ++rg) {
          const int m = mt * 16 + quad * 4 + rg;
          if (rv_l[m] == want)
            out[(size_t)TT * 256 + (size_t)(t0 + m) * 256 + n] =
                acc[mt][nt][rg] + pbv;
        }
    }
  }
}

// ---------------------------------------------------------------------------
extern "C" void kernel_launch(void* const* d_in, const int* in_sizes, int n_in,
                              void* d_out, int out_size, void* d_ws, size_t ws_size,
                              hipStream_t stream)
{
  const int*   q   = (const int*)d_in[0];
  const int*   r   = (const int*)d_in[1];
  const float* emb = (const float*)d_in[2];
  const float* ew1 = (const float*)d_in[3];
  const float* eb1 = (const float*)d_in[4];
  const float* ew2 = (const float*)d_in[5];
  const float* eb2 = (const float*)d_in[6];
  const float* aw  = (const float*)d_in[7];
  const float* ab  = (const float*)d_in[8];
  const float* rw  = (const float*)d_in[9];
  const float* rb  = (const float*)d_in[10];
  const float* st  = (const float*)d_in[11];
  const float* wih = (const float*)d_in[12];
  const float* whh = (const float*)d_in[13];
  const float* bih = (const float*)d_in[14];   // folded in prep via g_xgr/g_xg0
  const float* bhh = (const float*)d_in[15];
  const float* wgw = (const float*)d_in[16];
  const float* wgb = (const float*)d_in[17];
  const float* lng = (const float*)d_in[18];
  const float* lnb = (const float*)d_in[19];
  const float* resp= (const float*)d_in[20];
  const float* pcw = (const float*)d_in[21];
  const float* pcb = (const float*)d_in[22];
  const float* piw = (const float*)d_in[23];
  const float* pib = (const float*)d_in[24];
  float* out = (float*)d_out;
  (void)bih; (void)in_sizes; (void)n_in; (void)d_ws; (void)ws_size; (void)out_size;

  prep_kernel<<<64, 256, 0, stream>>>(ew1, ew2, pcw, piw, resp, rw, rb, st, wih, bih);
  qsk_kernel<<<dim3(157, 4), 256, 0, stream>>>(emb, aw, ab);
  smallk_kernel<<<NQ, 256, 0, stream>>>(rw, wih, wgw);
  gru_kernel<<<64, 256, 0, stream>>>(q, r, whh, bhh);
  top1_kernel<<<128, 256, 0, stream>>>(q, wgw, wgb);
  kernelE<<<313, 128, 0, stream>>>(emb, eb1, eb2, lng, lnb);
  kernelF<<<1024, 128, 0, stream>>>(q, r, pcb, pib, out);
}

// Round 4
// 1217.422 us; speedup vs baseline: 1.1921x; 1.1921x over previous
//
#include <hip/hip_runtime.h>
#include <cstddef>

// ---------------------------------------------------------------------------
// PolyaAKT interaction embedder, MI355X/gfx950.  Inputs fp32, output fp32.
// Control path (logits/GRU) high-precision for argmax fidelity; value path
// (experts/LN/proj) in bf16 MFMA.  Per-q dedup throughout.
// R4: GRU step = fp32 dots + fp64 Taylor-poly gates (guarded slow path),
// fp64 h carry; m stored fp32.  qsk reverted to fp32-LDS form (R3 regression).
// ---------------------------------------------------------------------------

#define NQ 10000
#define TT 32768   // B*S
#define GC 32      // GRU chunk steps

typedef __attribute__((ext_vector_type(8))) short bf16x8;
typedef __attribute__((ext_vector_type(4))) float f32x4;

__device__ double g_qs  [NQ * 256];      // q_summary (relu'd), fp64
__device__ double g_xgq [NQ * 192];      // gru_in_q @ W_ih^T
__device__ double g_xgr [2 * 192];       // r-part of xg (+b_ih)
__device__ double g_xg0 [192];           // start_token @ W_ih^T + b_ih
__device__ double g_lq  [NQ * 4];        // qs @ wgate[0:256]
__device__ float  g_m   [TT * 64];       // GRU hidden per token (fp32)
__device__ int    g_top1[TT];
__device__ unsigned short g_w1t  [4 * 256 * 256];  // bf16 [e][n][k]
__device__ unsigned short g_w2t  [4 * 256 * 256];
__device__ unsigned short g_projt[512 * 256];      // bf16 [n(cor|inc)][k]
__device__ unsigned short g_qf   [NQ * 4 * 256];   // LN'd expert out, bf16

__device__ __forceinline__ float bf2f(unsigned short x) {
  return __uint_as_float(((unsigned)x) << 16);
}
__device__ __forceinline__ unsigned short f2bf(float f) {
  unsigned u = __float_as_uint(f);
  u += 0x7FFFu + ((u >> 16) & 1u);   // RNE
  return (unsigned short)(u >> 16);
}
__device__ __forceinline__ f32x4 mfma16(bf16x8 a, bf16x8 b, f32x4 c) {
  return __builtin_amdgcn_mfma_f32_16x16x32_bf16(a, b, c, 0, 0, 0);
}

// fast fp64 exp (slow path only): range-reduced degree-10 poly, rel err ~2e-13.
__device__ __forceinline__ double fexp(double x) {
  const double L2E  = 1.4426950408889634074;
  const double LN2H = 6.93147180369123816490e-01;
  const double LN2L = 1.90821492927058770002e-10;
  double n = rint(x * L2E);
  int ni = (int)n;
  double r = fma(-n, LN2H, x);
  r = fma(-n, LN2L, r);
  double p = 2.7557319223985888e-07;
  p = fma(p, r, 2.7557319223985893e-06);
  p = fma(p, r, 2.4801587301587302e-05);
  p = fma(p, r, 1.9841269841269841e-04);
  p = fma(p, r, 1.3888888888888889e-03);
  p = fma(p, r, 8.3333333333333332e-03);
  p = fma(p, r, 4.1666666666666664e-02);
  p = fma(p, r, 1.6666666666666666e-01);
  p = fma(p, r, 0.5);
  p = fma(p, r, 1.0);
  p = fma(p, r, 1.0);
  return ldexp(p, ni);
}

// tanh via odd Taylor, |p| <= 0.25: abs err ~5e-11.
__device__ __forceinline__ double tpoly(double p) {
  const double p2 = p * p;
  double t = -1382.0 / 155925.0;          // p^11
  t = fma(t, p2, 62.0 / 2835.0);          // p^9
  t = fma(t, p2, -17.0 / 315.0);          // p^7
  t = fma(t, p2, 2.0 / 15.0);             // p^5
  t = fma(t, p2, -1.0 / 3.0);             // p^3
  t = fma(t, p2, 1.0);
  return p * t;
}

// ---------------------------------------------------------------------------
// prep: bf16 transposed weight tables + fp64 folds (xg_r, xg0).
// ---------------------------------------------------------------------------
__global__ void __launch_bounds__(256) prep_kernel(
    const float* __restrict__ expert_w1, const float* __restrict__ expert_w2,
    const float* __restrict__ proj_cor_w, const float* __restrict__ proj_inc_w,
    const float* __restrict__ resp_table, const float* __restrict__ reducer_w,
    const float* __restrict__ reducer_b,  const float* __restrict__ start_token,
    const float* __restrict__ gru_w_ih,   const float* __restrict__ gru_b_ih)
{
  __shared__ double red2f[128];   // [rr][j]
  const int tid = threadIdx.x;
  if (blockIdx.x == 0) {
    if (tid < 128) {
      const int rr = tid >> 6, j = tid & 63;
      double acc = (double)reducer_b[j];
      for (int k = 0; k < 256; ++k)
        acc += (double)resp_table[rr * 256 + k] *
               (double)reducer_w[(256 + k) * 64 + j];
      red2f[tid] = acc;
    }
    __syncthreads();
    if (tid < 192) {
      const double bih = (double)gru_b_ih[tid];
      double a0 = bih, a1 = bih, a2 = bih;
      for (int j = 0; j < 64; ++j) {
        const double w = (double)gru_w_ih[tid * 64 + j];
        a0 += red2f[j] * w;
        a1 += red2f[64 + j] * w;
        a2 += (double)start_token[j] * w;
      }
      g_xgr[tid] = a0; g_xgr[192 + tid] = a1; g_xg0[tid] = a2;
    }
  }
  const int idx0 = blockIdx.x * 256 + tid;
  const int stride = gridDim.x * 256;
  for (int i = idx0; i < 4 * 256 * 256; i += stride) {
    const int e = i >> 16, rem = i & 65535, n = rem >> 8, k = rem & 255;
    g_w1t[i] = f2bf(expert_w1[e * 65536 + k * 256 + n]);
    g_w2t[i] = f2bf(expert_w2[e * 65536 + k * 256 + n]);
  }
  for (int i = idx0; i < 512 * 256; i += stride) {
    const int n = i >> 8, k = i & 255;
    g_projt[i] = f2bf((n < 256) ? proj_cor_w[k * 256 + n]
                                : proj_inc_w[k * 256 + (n - 256)]);
  }
}

// ---------------------------------------------------------------------------
// qsk: fp64 GEMM  qs[q][n] = relu( emb_row_q(1024) . adapter_w[:,n] + b[n] )
// (round-2 form: fp32 LDS tiles, cvt at use).
// ---------------------------------------------------------------------------
__global__ void __launch_bounds__(256) qsk_kernel(
    const float* __restrict__ emb, const float* __restrict__ adapter_w,
    const float* __restrict__ adapter_b)
{
  __shared__ __align__(16) float As[64][33];
  __shared__ __align__(16) float Bs[32][65];
  const int tid = threadIdx.x;
  const int q0 = blockIdx.x * 64;
  const int n0 = blockIdx.y * 64;
  const int ty = tid >> 4, tx = tid & 15;

  double acc[4][4];
#pragma unroll
  for (int i = 0; i < 4; ++i)
#pragma unroll
    for (int j = 0; j < 4; ++j) acc[i][j] = 0.0;

  const int arow = tid >> 2, aks = (tid & 3) * 8;
  const int qa = min(q0 + arow, NQ - 1);
  const int bkk = tid >> 3, bns = (tid & 7) * 8;

  for (int kc = 0; kc < 1024; kc += 32) {
    f32x4 av0 = *(const f32x4*)(emb + (size_t)qa * 1024 + kc + aks);
    f32x4 av1 = *(const f32x4*)(emb + (size_t)qa * 1024 + kc + aks + 4);
    f32x4 bv0 = *(const f32x4*)(adapter_w + (size_t)(kc + bkk) * 256 + n0 + bns);
    f32x4 bv1 = *(const f32x4*)(adapter_w + (size_t)(kc + bkk) * 256 + n0 + bns + 4);
    __syncthreads();
#pragma unroll
    for (int i = 0; i < 4; ++i) { As[arow][aks + i] = av0[i]; As[arow][aks + 4 + i] = av1[i]; }
#pragma unroll
    for (int i = 0; i < 4; ++i) { Bs[bkk][bns + i] = bv0[i]; Bs[bkk][bns + 4 + i] = bv1[i]; }
    __syncthreads();
#pragma unroll 4
    for (int kk = 0; kk < 32; ++kk) {
      double a[4], b[4];
#pragma unroll
      for (int i = 0; i < 4; ++i) a[i] = (double)As[ty * 4 + i][kk];
#pragma unroll
      for (int j = 0; j < 4; ++j) b[j] = (double)Bs[kk][tx * 4 + j];
#pragma unroll
      for (int i = 0; i < 4; ++i)
#pragma unroll
        for (int j = 0; j < 4; ++j) acc[i][j] = fma(a[i], b[j], acc[i][j]);
    }
  }
#pragma unroll
  for (int i = 0; i < 4; ++i) {
    const int qrow = q0 + ty * 4 + i;
    if (qrow < NQ) {
#pragma unroll
      for (int j = 0; j < 4; ++j) {
        const int n = n0 + tx * 4 + j;
        double v = acc[i][j] + (double)adapter_b[n];
        g_qs[(size_t)qrow * 256 + n] = v > 0.0 ? v : 0.0;
      }
    }
  }
}

// ---------------------------------------------------------------------------
// smallk: per q -> gru_in_q(64), xg_q(192), lq(4).  One block per q, 4-way ILP.
// ---------------------------------------------------------------------------
__global__ void __launch_bounds__(256) smallk_kernel(
    const float* __restrict__ reducer_w, const float* __restrict__ gru_w_ih,
    const float* __restrict__ wgate_w)
{
  __shared__ double qsr[256];
  __shared__ double ps[4][64];
  __shared__ double gi[64];
  const int tid = threadIdx.x;
  const int qq = blockIdx.x;
  qsr[tid] = g_qs[(size_t)qq * 256 + tid];
  __syncthreads();
  {
    const int j = tid & 63, h = tid >> 6;
    const int k0 = h * 64;
    double a0 = 0.0, a1 = 0.0, a2 = 0.0, a3 = 0.0;
    for (int k = 0; k < 64; k += 4) {
      a0 = fma(qsr[k0 + k + 0], (double)reducer_w[(k0 + k + 0) * 64 + j], a0);
      a1 = fma(qsr[k0 + k + 1], (double)reducer_w[(k0 + k + 1) * 64 + j], a1);
      a2 = fma(qsr[k0 + k + 2], (double)reducer_w[(k0 + k + 2) * 64 + j], a2);
      a3 = fma(qsr[k0 + k + 3], (double)reducer_w[(k0 + k + 3) * 64 + j], a3);
    }
    ps[h][j] = (a0 + a1) + (a2 + a3);
  }
  __syncthreads();
  if (tid < 64) gi[tid] = (ps[0][tid] + ps[1][tid]) + (ps[2][tid] + ps[3][tid]);
  if (tid >= 64 && tid < 68) {
    const int e = tid - 64;
    double a0 = 0.0, a1 = 0.0, a2 = 0.0, a3 = 0.0;
    for (int k = 0; k < 256; k += 4) {
      a0 = fma(qsr[k + 0], (double)wgate_w[(k + 0) * 4 + e], a0);
      a1 = fma(qsr[k + 1], (double)wgate_w[(k + 1) * 4 + e], a1);
      a2 = fma(qsr[k + 2], (double)wgate_w[(k + 2) * 4 + e], a2);
      a3 = fma(qsr[k + 3], (double)wgate_w[(k + 3) * 4 + e], a3);
    }
    g_lq[(size_t)qq * 4 + e] = (a0 + a1) + (a2 + a3);
  }
  __syncthreads();
  if (tid < 192) {
    double a0 = 0.0, a1 = 0.0, a2 = 0.0, a3 = 0.0;
    for (int k = 0; k < 64; k += 4) {
      a0 = fma(gi[k + 0], (double)gru_w_ih[tid * 64 + k + 0], a0);
      a1 = fma(gi[k + 1], (double)gru_w_ih[tid * 64 + k + 1], a1);
      a2 = fma(gi[k + 2], (double)gru_w_ih[tid * 64 + k + 2], a2);
      a3 = fma(gi[k + 3], (double)gru_w_ih[tid * 64 + k + 3], a3);
    }
    g_xgq[(size_t)qq * 192 + tid] = (a0 + a1) + (a2 + a3);
  }
}

// ---------------------------------------------------------------------------
// gru: mixed-precision scan.  64 blocks x 256 threads.
// Thread (wave w, lane l): j = w*16+(l&15), k-slice c = l>>4.
// fp32 dots (h fp32 in HF), fp64 carry (HD) + fp64 Taylor gates.
// One barrier per step; x gathered / m flushed in GC-step chunks.
// ---------------------------------------------------------------------------
__global__ void __launch_bounds__(256) gru_kernel(
    const int* __restrict__ q, const int* __restrict__ r,
    const float* __restrict__ whh, const float* __restrict__ bhh)
{
  __shared__ __align__(16) double XL[GC][192];
  __shared__ __align__(16) float  MB[GC][64];
  __shared__ __align__(16) float  HF[2][64];
  __shared__ __align__(16) double HD[2][64];
  __shared__ int OQ[GC], OR[GC];
  const int tid = threadIdx.x;
  const int w = tid >> 6, lane = tid & 63;
  const int j = w * 16 + (lane & 15);
  const int c = lane >> 4;
  const int b = blockIdx.x;

  float Wr[16], Wz[16], Wn[16];
#pragma unroll
  for (int i = 0; i < 16; ++i) {
    Wr[i] = whh[(0 * 64 + j) * 64 + c * 16 + i];
    Wz[i] = whh[(1 * 64 + j) * 64 + c * 16 + i];
    Wn[i] = whh[(2 * 64 + j) * 64 + c * 16 + i];
  }
  const double br = (double)bhh[j];
  const double bz = (double)bhh[64 + j];
  const double bn = (double)bhh[128 + j];
  if (tid < 64) { HF[0][tid] = 0.f; HD[0][tid] = 0.0; }

  int p = 0;
  for (int cc = 0; cc < 512 / GC; ++cc) {
    if (tid < GC) {
      const int s = cc * GC + tid;
      if (s == 0) { OQ[tid] = -1; OR[tid] = 0; }
      else {
        OQ[tid] = q[b * 512 + s - 1] * 192;
        OR[tid] = r[b * 512 + s - 1] * 192;
      }
    }
    __syncthreads();
    if (tid < 192) {
#pragma unroll 8
      for (int sc = 0; sc < GC; ++sc) {
        const int o = OQ[sc];
        double v;
        if (o < 0) v = g_xg0[tid];
        else       v = g_xgq[(size_t)o + tid] + g_xgr[OR[sc] + tid];
        XL[sc][tid] = v;
      }
    }
    __syncthreads();

    for (int sc = 0; sc < GC; ++sc) {
      float h16[16];
      const f32x4* hp = (const f32x4*)&HF[p][c * 16];
#pragma unroll
      for (int i = 0; i < 4; ++i) {
        f32x4 t4 = hp[i];
        h16[4 * i] = t4[0]; h16[4 * i + 1] = t4[1];
        h16[4 * i + 2] = t4[2]; h16[4 * i + 3] = t4[3];
      }
      float ar0 = 0.f, ar1 = 0.f, az0 = 0.f, az1 = 0.f, an0 = 0.f, an1 = 0.f;
#pragma unroll
      for (int i = 0; i < 8; ++i) {
        ar0 = fmaf(Wr[2 * i], h16[2 * i], ar0);
        ar1 = fmaf(Wr[2 * i + 1], h16[2 * i + 1], ar1);
        az0 = fmaf(Wz[2 * i], h16[2 * i], az0);
        az1 = fmaf(Wz[2 * i + 1], h16[2 * i + 1], az1);
        an0 = fmaf(Wn[2 * i], h16[2 * i], an0);
        an1 = fmaf(Wn[2 * i + 1], h16[2 * i + 1], an1);
      }
      float hrf = ar0 + ar1, hzf = az0 + az1, hnf = an0 + an1;
      hrf += __shfl_xor(hrf, 16); hzf += __shfl_xor(hzf, 16); hnf += __shfl_xor(hnf, 16);
      hrf += __shfl_xor(hrf, 32); hzf += __shfl_xor(hzf, 32); hnf += __shfl_xor(hnf, 32);
      const double hr = br + (double)hrf;
      const double hz = bz + (double)hzf;
      const double hn = bn + (double)hnf;
      const double xr = XL[sc][j], xz = XL[sc][64 + j], xn = XL[sc][128 + j];
      const double pr = xr + hr, pz = xz + hz;
      double rg = fma(0.5, tpoly(0.5 * pr), 0.5);
      double zg = fma(0.5, tpoly(0.5 * pz), 0.5);
      double pre = fma(rg, hn, xn);
      double ng = tpoly(pre);
      const bool bad = (fabs(pr) > 0.5) | (fabs(pz) > 0.5) | (fabs(pre) > 0.25);
      if (bad) {   // rare slow path, execz-skipped normally
        rg = 1.0 / (1.0 + fexp(-pr));
        zg = 1.0 / (1.0 + fexp(-pz));
        pre = fma(rg, hn, xn);
        ng = 1.0 - 2.0 / (fexp(pre + pre) + 1.0);
      }
      const double hd = HD[p][j];
      const double hnew = fma(zg, hd - ng, ng);   // (1-z)n + z h
      if (c == 0) {
        HF[p ^ 1][j] = (float)hnew;
        HD[p ^ 1][j] = hnew;
        MB[sc][j] = (float)hnew;
      }
      __syncthreads();
      p ^= 1;
    }

    // flush m chunk (coalesced, fp32); drains at next chunk's barrier
#pragma unroll
    for (int i2 = 0; i2 < GC * 64 / 256; ++i2) {
      const int e = i2 * 256 + tid;
      const int sc = e >> 6, jj = e & 63;
      g_m[((size_t)b * 512 + cc * GC + sc) * 64 + jj] = MB[sc][jj];
    }
  }
}

// ---------------------------------------------------------------------------
// top1: logits = lq[q_t] + m_t @ wgate[256:320] + wgate_b ; first-max argmax.
// ---------------------------------------------------------------------------
__global__ void __launch_bounds__(256) top1_kernel(
    const int* __restrict__ q,
    const float* __restrict__ wgate_w, const float* __restrict__ wgate_b)
{
  __shared__ double w2[256];   // [j][e]
  const int tid = threadIdx.x;
  w2[tid] = (double)wgate_w[1024 + tid];
  __syncthreads();
  const int t = blockIdx.x * 256 + tid;
  const int qv = q[t];
  double l0 = g_lq[(size_t)qv * 4 + 0] + (double)wgate_b[0];
  double l1 = g_lq[(size_t)qv * 4 + 1] + (double)wgate_b[1];
  double l2 = g_lq[(size_t)qv * 4 + 2] + (double)wgate_b[2];
  double l3 = g_lq[(size_t)qv * 4 + 3] + (double)wgate_b[3];
  const float* mr = g_m + (size_t)t * 64;
  for (int jj = 0; jj < 64; ++jj) {
    const double mv = (double)mr[jj];
    l0 = fma(mv, w2[jj * 4 + 0], l0);
    l1 = fma(mv, w2[jj * 4 + 1], l1);
    l2 = fma(mv, w2[jj * 4 + 2], l2);
    l3 = fma(mv, w2[jj * 4 + 3], l3);
  }
  int bi = 0; double bvv = l0;
  if (l1 > bvv) { bvv = l1; bi = 1; }
  if (l2 > bvv) { bvv = l2; bi = 2; }
  if (l3 > bvv) { bvv = l3; bi = 3; }
  g_top1[t] = bi;
}

// ---------------------------------------------------------------------------
// kernelE: per 32 q-values: stage emb rows as bf16; for each expert e:
// h1=relu(qr_e@W1+b1) -> out=h1@W2+b2 -> LN -> qf[q][e] bf16.
// ---------------------------------------------------------------------------
__global__ void __launch_bounds__(128) kernelE(
    const float* __restrict__ emb,
    const float* __restrict__ b1, const float* __restrict__ b2,
    const float* __restrict__ lng, const float* __restrict__ lnb)
{
  __shared__ __align__(16) unsigned short QR[32 * 1032];
  __shared__ __align__(16) unsigned short H1[32 * 264];
  __shared__ __align__(16) unsigned short EO[32 * 264];
  const int tid = threadIdx.x;
  const int t0 = blockIdx.x * 32;
  const int w = tid >> 6;
  const int lane = tid & 63;
  const int l15 = lane & 15;
  const int quad = lane >> 4;

  for (int c = 0; c < 64; ++c) {
    const int idx = c * 128 + tid;
    const int row = idx >> 8, col4 = idx & 255;
    const int qv = min(t0 + row, NQ - 1);
    f32x4 v = *(const f32x4*)(emb + (size_t)qv * 1024 + col4 * 4);
    unsigned a = ((unsigned)f2bf(v[1]) << 16) | f2bf(v[0]);
    unsigned bb = ((unsigned)f2bf(v[3]) << 16) | f2bf(v[2]);
    *(uint2*)&QR[row * 1032 + col4 * 4] = make_uint2(a, bb);
  }
  __syncthreads();

  const f32x4 z4 = {0.f, 0.f, 0.f, 0.f};
  const int n0 = w * 128;

  for (int e = 0; e < 4; ++e) {
    f32x4 acc[2][8];
#pragma unroll
    for (int a = 0; a < 2; ++a)
#pragma unroll
      for (int bq = 0; bq < 8; ++bq) acc[a][bq] = z4;
#pragma unroll
    for (int ks = 0; ks < 8; ++ks) {
      const int koff = e * 256 + ks * 32 + quad * 8;
      bf16x8 a0 = *(const bf16x8*)&QR[l15 * 1032 + koff];
      bf16x8 a1 = *(const bf16x8*)&QR[(16 + l15) * 1032 + koff];
      const int kb = ks * 32 + quad * 8;
#pragma unroll
      for (int nt = 0; nt < 8; ++nt) {
        bf16x8 bbv = *(const bf16x8*)(g_w1t + (size_t)e * 65536 +
                                      (size_t)(n0 + nt * 16 + l15) * 256 + kb);
        acc[0][nt] = mfma16(a0, bbv, acc[0][nt]);
        acc[1][nt] = mfma16(a1, bbv, acc[1][nt]);
      }
    }
#pragma unroll
    for (int nt = 0; nt < 8; ++nt) {
      const int n = n0 + nt * 16 + l15;
      const float b1v = b1[e * 256 + n];
#pragma unroll
      for (int mt = 0; mt < 2; ++mt)
#pragma unroll
        for (int rg = 0; rg < 4; ++rg) {
          const int m = mt * 16 + quad * 4 + rg;
          H1[m * 264 + n] = f2bf(fmaxf(acc[mt][nt][rg] + b1v, 0.f));
        }
    }
    __syncthreads();
    f32x4 acc2[2][8];
#pragma unroll
    for (int a = 0; a < 2; ++a)
#pragma unroll
      for (int bq = 0; bq < 8; ++bq) acc2[a][bq] = z4;
#pragma unroll
    for (int ks = 0; ks < 8; ++ks) {
      const int koff = ks * 32 + quad * 8;
      bf16x8 a0 = *(const bf16x8*)&H1[l15 * 264 + koff];
      bf16x8 a1 = *(const bf16x8*)&H1[(16 + l15) * 264 + koff];
#pragma unroll
      for (int nt = 0; nt < 8; ++nt) {
        bf16x8 bbv = *(const bf16x8*)(g_w2t + (size_t)e * 65536 +
                                      (size_t)(n0 + nt * 16 + l15) * 256 + koff);
        acc2[0][nt] = mfma16(a0, bbv, acc2[0][nt]);
        acc2[1][nt] = mfma16(a1, bbv, acc2[1][nt]);
      }
    }
#pragma unroll
    for (int nt = 0; nt < 8; ++nt) {
      const int n = n0 + nt * 16 + l15;
      const float b2v = b2[e * 256 + n];
#pragma unroll
      for (int mt = 0; mt < 2; ++mt)
#pragma unroll
        for (int rg = 0; rg < 4; ++rg) {
          const int m = mt * 16 + quad * 4 + rg;
          EO[m * 264 + n] = f2bf(acc2[mt][nt][rg] + b2v);
        }
    }
    __syncthreads();
    {
      const int m = tid >> 2;
      const int sub = tid & 3;
      float sx = 0.f, sxx = 0.f;
#pragma unroll
      for (int i = 0; i < 8; ++i) {
        bf16x8 v = *(const bf16x8*)&EO[m * 264 + sub * 64 + i * 8];
#pragma unroll
        for (int c = 0; c < 8; ++c) {
          const float f = bf2f((unsigned short)v[c]);
          sx += f; sxx += f * f;
        }
      }
      sx += __shfl_xor(sx, 1); sxx += __shfl_xor(sxx, 1);
      sx += __shfl_xor(sx, 2); sxx += __shfl_xor(sxx, 2);
      const float mu = sx * (1.f / 256.f);
      const float var = sxx * (1.f / 256.f) - mu * mu;
      const float inv = 1.f / sqrtf(var + 1e-5f);
      if (t0 + m < NQ) {
        const size_t base = ((size_t)(t0 + m) * 4 + e) * 256;
#pragma unroll
        for (int i = 0; i < 8; ++i) {
          const int dbase = sub * 64 + i * 8;
          bf16x8 v = *(const bf16x8*)&EO[m * 264 + dbase];
          bf16x8 ov;
#pragma unroll
          for (int c = 0; c < 8; ++c) {
            const int d = dbase + c;
            const float f = bf2f((unsigned short)v[c]);
            ov[c] = (short)f2bf(lng[d] * (f - mu) * inv + lnb[d]);
          }
          *(bf16x8*)(g_qf + base + dbase) = ov;
        }
      }
    }
    __syncthreads();
  }
}

// ---------------------------------------------------------------------------
// kernelF: per 32 tokens: gather qf[q_t][top1_t] -> q_fused out (fp32) and
// LDS; proj (cor|inc) bf16 MFMA; qa_fused by r.
// ---------------------------------------------------------------------------
__global__ void __launch_bounds__(128) kernelF(
    const int* __restrict__ q, const int* __restrict__ r,
    const float* __restrict__ pcb, const float* __restrict__ pib,
    float* __restrict__ out)
{
  __shared__ __align__(16) unsigned short QF[32 * 264];
  __shared__ int rv_l[32];
  const int tid = threadIdx.x;
  const int t0 = blockIdx.x * 32;
  const int w = tid >> 6;
  const int lane = tid & 63;
  const int l15 = lane & 15;
  const int quad = lane >> 4;
  if (tid < 32) rv_l[tid] = r[t0 + tid];
  __syncthreads();

  {
    const int m = tid >> 2;
    const size_t row = ((size_t)q[t0 + m] * 4 + g_top1[t0 + m]) * 256;
#pragma unroll
    for (int i = 0; i < 8; ++i) {
      const int dbase = (tid & 3) * 64 + i * 8;
      bf16x8 v = *(const bf16x8*)(g_qf + row + dbase);
      *(bf16x8*)&QF[m * 264 + dbase] = v;
      f32x4 f0, f1;
#pragma unroll
      for (int c = 0; c < 4; ++c) f0[c] = bf2f((unsigned short)v[c]);
#pragma unroll
      for (int c = 0; c < 4; ++c) f1[c] = bf2f((unsigned short)v[4 + c]);
      *(f32x4*)(out + (size_t)(t0 + m) * 256 + dbase) = f0;
      *(f32x4*)(out + (size_t)(t0 + m) * 256 + dbase + 4) = f1;
    }
  }
  __syncthreads();

  const f32x4 z4 = {0.f, 0.f, 0.f, 0.f};
  const int n0 = w * 128;
  for (int ph = 0; ph < 2; ++ph) {
    f32x4 acc[2][8];
#pragma unroll
    for (int a = 0; a < 2; ++a)
#pragma unroll
      for (int bq = 0; bq < 8; ++bq) acc[a][bq] = z4;
#pragma unroll
    for (int ks = 0; ks < 8; ++ks) {
      const int koff = ks * 32 + quad * 8;
      bf16x8 a0 = *(const bf16x8*)&QF[l15 * 264 + koff];
      bf16x8 a1 = *(const bf16x8*)&QF[(16 + l15) * 264 + koff];
#pragma unroll
      for (int nt = 0; nt < 8; ++nt) {
        bf16x8 bbv = *(const bf16x8*)(g_projt +
            (size_t)(ph * 256 + n0 + nt * 16 + l15) * 256 + koff);
        acc[0][nt] = mfma16(a0, bbv, acc[0][nt]);
        acc[1][nt] = mfma16(a1, bbv, acc[1][nt]);
      }
    }
    const float* pbb = ph ? pib : pcb;
    const int want = ph ? 0 : 1;
#pragma unroll
    for (int nt = 0; nt < 8; ++nt) {
      const int n = n0 + nt * 16 + l15;
      const float pbv = pbb[n];
#pragma unroll
      for (int mt = 0; mt < 2; ++mt)
#pragma unroll
        for (int rg = 0; rg < 4; ++rg) {
          const int m = mt * 16 + quad * 4 + rg;
          if (rv_l[m] == want)
            out[(size_t)TT * 256 + (size_t)(t0 + m) * 256 + n] =
                acc[mt][nt][rg] + pbv;
        }
    }
  }
}

// ---------------------------------------------------------------------------
extern "C" void kernel_launch(void* const* d_in, const int* in_sizes, int n_in,
                              void* d_out, int out_size, void* d_ws, size_t ws_size,
                              hipStream_t stream)
{
  const int*   q   = (const int*)d_in[0];
  const int*   r   = (const int*)d_in[1];
  const float* emb = (const float*)d_in[2];
  const float* ew1 = (const float*)d_in[3];
  const float* eb1 = (const float*)d_in[4];
  const float* ew2 = (const float*)d_in[5];
  const float* eb2 = (const float*)d_in[6];
  const float* aw  = (const float*)d_in[7];
  const float* ab  = (const float*)d_in[8];
  const float* rw  = (const float*)d_in[9];
  const float* rb  = (const float*)d_in[10];
  const float* st  = (const float*)d_in[11];
  const float* wih = (const float*)d_in[12];
  const float* whh = (const float*)d_in[13];
  const float* bih = (const float*)d_in[14];
  const float* bhh = (const float*)d_in[15];
  const float* wgw = (const float*)d_in[16];
  const float* wgb = (const float*)d_in[17];
  const float* lng = (const float*)d_in[18];
  const float* lnb = (const float*)d_in[19];
  const float* resp= (const float*)d_in[20];
  const float* pcw = (const float*)d_in[21];
  const float* pcb = (const float*)d_in[22];
  const float* piw = (const float*)d_in[23];
  const float* pib = (const float*)d_in[24];
  float* out = (float*)d_out;
  (void)bih; (void)in_sizes; (void)n_in; (void)d_ws; (void)ws_size; (void)out_size;

  prep_kernel<<<64, 256, 0, stream>>>(ew1, ew2, pcw, piw, resp, rw, rb, st, wih, bih);
  qsk_kernel<<<dim3(157, 4), 256, 0, stream>>>(emb, aw, ab);
  smallk_kernel<<<NQ, 256, 0, stream>>>(rw, wih, wgw);
  gru_kernel<<<64, 256, 0, stream>>>(q, r, whh, bhh);
  top1_kernel<<<128, 256, 0, stream>>>(q, wgw, wgb);
  kernelE<<<313, 128, 0, stream>>>(emb, eb1, eb2, lng, lnb);
  kernelF<<<1024, 128, 0, stream>>>(q, r, pcb, pib, out);
}

// Round 5
// 1092.701 us; speedup vs baseline: 1.3282x; 1.1141x over previous
//
#include <hip/hip_runtime.h>
#include <cstddef>

// ---------------------------------------------------------------------------
// PolyaAKT interaction embedder, MI355X/gfx950.  Inputs fp32, output fp32.
// Control path (logits/GRU) high-precision for argmax fidelity; value path
// (experts/LN/proj) in bf16 MFMA.  Per-q dedup throughout.
// R5: GRU = one wave per sequence, zero barriers: h mirrored in wave-private
// LDS (lane j owns h[j], full r/z/n dots per lane, no shuffles), W_hh in
// VGPRs (launch_bounds(64,1) -> up to 512 VGPRs), x staged fp32 per 8-step
// chunk with 1-chunk software pipeline + 2-chunk q/r lookahead.
// ---------------------------------------------------------------------------

#define NQ 10000
#define TT 32768   // B*S
#define GW 8       // GRU chunk steps

typedef __attribute__((ext_vector_type(8))) short bf16x8;
typedef __attribute__((ext_vector_type(4))) float f32x4;

__device__ double g_qs  [NQ * 256];      // q_summary (relu'd), fp64
__device__ float  g_xgf [NQ * 192];      // gru_in_q @ W_ih^T (fp32)
__device__ double g_xgr [2 * 192];       // r-part of xg (+b_ih), fp64
__device__ float  g_xg0f[192];           // start_token @ W_ih^T + b_ih (fp32)
__device__ double g_lq  [NQ * 4];        // qs @ wgate[0:256]
__device__ float  g_m   [TT * 64];       // GRU hidden per token (fp32)
__device__ int    g_top1[TT];
__device__ unsigned short g_w1t  [4 * 256 * 256];  // bf16 [e][n][k]
__device__ unsigned short g_w2t  [4 * 256 * 256];
__device__ unsigned short g_projt[512 * 256];      // bf16 [n(cor|inc)][k]
__device__ unsigned short g_qf   [NQ * 4 * 256];   // LN'd expert out, bf16

__device__ __forceinline__ float bf2f(unsigned short x) {
  return __uint_as_float(((unsigned)x) << 16);
}
__device__ __forceinline__ unsigned short f2bf(float f) {
  unsigned u = __float_as_uint(f);
  u += 0x7FFFu + ((u >> 16) & 1u);   // RNE
  return (unsigned short)(u >> 16);
}
__device__ __forceinline__ f32x4 mfma16(bf16x8 a, bf16x8 b, f32x4 c) {
  return __builtin_amdgcn_mfma_f32_16x16x32_bf16(a, b, c, 0, 0, 0);
}

// fast fp64 exp (slow path only): range-reduced degree-10 poly, rel err ~2e-13.
__device__ __forceinline__ double fexp(double x) {
  const double L2E  = 1.4426950408889634074;
  const double LN2H = 6.93147180369123816490e-01;
  const double LN2L = 1.90821492927058770002e-10;
  double n = rint(x * L2E);
  int ni = (int)n;
  double r = fma(-n, LN2H, x);
  r = fma(-n, LN2L, r);
  double p = 2.7557319223985888e-07;
  p = fma(p, r, 2.7557319223985893e-06);
  p = fma(p, r, 2.4801587301587302e-05);
  p = fma(p, r, 1.9841269841269841e-04);
  p = fma(p, r, 1.3888888888888889e-03);
  p = fma(p, r, 8.3333333333333332e-03);
  p = fma(p, r, 4.1666666666666664e-02);
  p = fma(p, r, 1.6666666666666666e-01);
  p = fma(p, r, 0.5);
  p = fma(p, r, 1.0);
  p = fma(p, r, 1.0);
  return ldexp(p, ni);
}

// tanh via odd Taylor, |p| <= 0.25: abs err ~5e-11.
__device__ __forceinline__ double tpoly(double p) {
  const double p2 = p * p;
  double t = -1382.0 / 155925.0;          // p^11
  t = fma(t, p2, 62.0 / 2835.0);          // p^9
  t = fma(t, p2, -17.0 / 315.0);          // p^7
  t = fma(t, p2, 2.0 / 15.0);             // p^5
  t = fma(t, p2, -1.0 / 3.0);             // p^3
  t = fma(t, p2, 1.0);
  return p * t;
}

// ---------------------------------------------------------------------------
// prep: bf16 transposed weight tables + fp64 folds (xg_r, xg0).
// ---------------------------------------------------------------------------
__global__ void __launch_bounds__(256) prep_kernel(
    const float* __restrict__ expert_w1, const float* __restrict__ expert_w2,
    const float* __restrict__ proj_cor_w, const float* __restrict__ proj_inc_w,
    const float* __restrict__ resp_table, const float* __restrict__ reducer_w,
    const float* __restrict__ reducer_b,  const float* __restrict__ start_token,
    const float* __restrict__ gru_w_ih,   const float* __restrict__ gru_b_ih)
{
  __shared__ double red2f[128];   // [rr][j]
  const int tid = threadIdx.x;
  if (blockIdx.x == 0) {
    if (tid < 128) {
      const int rr = tid >> 6, j = tid & 63;
      double acc = (double)reducer_b[j];
      for (int k = 0; k < 256; ++k)
        acc += (double)resp_table[rr * 256 + k] *
               (double)reducer_w[(256 + k) * 64 + j];
      red2f[tid] = acc;
    }
    __syncthreads();
    if (tid < 192) {
      const double bih = (double)gru_b_ih[tid];
      double a0 = bih, a1 = bih, a2 = bih;
      for (int j = 0; j < 64; ++j) {
        const double w = (double)gru_w_ih[tid * 64 + j];
        a0 += red2f[j] * w;
        a1 += red2f[64 + j] * w;
        a2 += (double)start_token[j] * w;
      }
      g_xgr[tid] = a0; g_xgr[192 + tid] = a1; g_xg0f[tid] = (float)a2;
    }
  }
  const int idx0 = blockIdx.x * 256 + tid;
  const int stride = gridDim.x * 256;
  for (int i = idx0; i < 4 * 256 * 256; i += stride) {
    const int e = i >> 16, rem = i & 65535, n = rem >> 8, k = rem & 255;
    g_w1t[i] = f2bf(expert_w1[e * 65536 + k * 256 + n]);
    g_w2t[i] = f2bf(expert_w2[e * 65536 + k * 256 + n]);
  }
  for (int i = idx0; i < 512 * 256; i += stride) {
    const int n = i >> 8, k = i & 255;
    g_projt[i] = f2bf((n < 256) ? proj_cor_w[k * 256 + n]
                                : proj_inc_w[k * 256 + (n - 256)]);
  }
}

// ---------------------------------------------------------------------------
// qsk: fp64 GEMM  qs[q][n] = relu( emb_row_q(1024) . adapter_w[:,n] + b[n] )
// ---------------------------------------------------------------------------
__global__ void __launch_bounds__(256) qsk_kernel(
    const float* __restrict__ emb, const float* __restrict__ adapter_w,
    const float* __restrict__ adapter_b)
{
  __shared__ __align__(16) float As[64][33];
  __shared__ __align__(16) float Bs[32][65];
  const int tid = threadIdx.x;
  const int q0 = blockIdx.x * 64;
  const int n0 = blockIdx.y * 64;
  const int ty = tid >> 4, tx = tid & 15;

  double acc[4][4];
#pragma unroll
  for (int i = 0; i < 4; ++i)
#pragma unroll
    for (int j = 0; j < 4; ++j) acc[i][j] = 0.0;

  const int arow = tid >> 2, aks = (tid & 3) * 8;
  const int qa = min(q0 + arow, NQ - 1);
  const int bkk = tid >> 3, bns = (tid & 7) * 8;

  for (int kc = 0; kc < 1024; kc += 32) {
    f32x4 av0 = *(const f32x4*)(emb + (size_t)qa * 1024 + kc + aks);
    f32x4 av1 = *(const f32x4*)(emb + (size_t)qa * 1024 + kc + aks + 4);
    f32x4 bv0 = *(const f32x4*)(adapter_w + (size_t)(kc + bkk) * 256 + n0 + bns);
    f32x4 bv1 = *(const f32x4*)(adapter_w + (size_t)(kc + bkk) * 256 + n0 + bns + 4);
    __syncthreads();
#pragma unroll
    for (int i = 0; i < 4; ++i) { As[arow][aks + i] = av0[i]; As[arow][aks + 4 + i] = av1[i]; }
#pragma unroll
    for (int i = 0; i < 4; ++i) { Bs[bkk][bns + i] = bv0[i]; Bs[bkk][bns + 4 + i] = bv1[i]; }
    __syncthreads();
#pragma unroll 4
    for (int kk = 0; kk < 32; ++kk) {
      double a[4], b[4];
#pragma unroll
      for (int i = 0; i < 4; ++i) a[i] = (double)As[ty * 4 + i][kk];
#pragma unroll
      for (int j = 0; j < 4; ++j) b[j] = (double)Bs[kk][tx * 4 + j];
#pragma unroll
      for (int i = 0; i < 4; ++i)
#pragma unroll
        for (int j = 0; j < 4; ++j) acc[i][j] = fma(a[i], b[j], acc[i][j]);
    }
  }
#pragma unroll
  for (int i = 0; i < 4; ++i) {
    const int qrow = q0 + ty * 4 + i;
    if (qrow < NQ) {
#pragma unroll
      for (int j = 0; j < 4; ++j) {
        const int n = n0 + tx * 4 + j;
        double v = acc[i][j] + (double)adapter_b[n];
        g_qs[(size_t)qrow * 256 + n] = v > 0.0 ? v : 0.0;
      }
    }
  }
}

// ---------------------------------------------------------------------------
// smallk: per q -> gru_in_q(64), xg_q(192) fp32, lq(4).  One block per q.
// ---------------------------------------------------------------------------
__global__ void __launch_bounds__(256) smallk_kernel(
    const float* __restrict__ reducer_w, const float* __restrict__ gru_w_ih,
    const float* __restrict__ wgate_w)
{
  __shared__ double qsr[256];
  __shared__ double ps[4][64];
  __shared__ double gi[64];
  const int tid = threadIdx.x;
  const int qq = blockIdx.x;
  qsr[tid] = g_qs[(size_t)qq * 256 + tid];
  __syncthreads();
  {
    const int j = tid & 63, h = tid >> 6;
    const int k0 = h * 64;
    double a0 = 0.0, a1 = 0.0, a2 = 0.0, a3 = 0.0;
    for (int k = 0; k < 64; k += 4) {
      a0 = fma(qsr[k0 + k + 0], (double)reducer_w[(k0 + k + 0) * 64 + j], a0);
      a1 = fma(qsr[k0 + k + 1], (double)reducer_w[(k0 + k + 1) * 64 + j], a1);
      a2 = fma(qsr[k0 + k + 2], (double)reducer_w[(k0 + k + 2) * 64 + j], a2);
      a3 = fma(qsr[k0 + k + 3], (double)reducer_w[(k0 + k + 3) * 64 + j], a3);
    }
    ps[h][j] = (a0 + a1) + (a2 + a3);
  }
  __syncthreads();
  if (tid < 64) gi[tid] = (ps[0][tid] + ps[1][tid]) + (ps[2][tid] + ps[3][tid]);
  if (tid >= 64 && tid < 68) {
    const int e = tid - 64;
    double a0 = 0.0, a1 = 0.0, a2 = 0.0, a3 = 0.0;
    for (int k = 0; k < 256; k += 4) {
      a0 = fma(qsr[k + 0], (double)wgate_w[(k + 0) * 4 + e], a0);
      a1 = fma(qsr[k + 1], (double)wgate_w[(k + 1) * 4 + e], a1);
      a2 = fma(qsr[k + 2], (double)wgate_w[(k + 2) * 4 + e], a2);
      a3 = fma(qsr[k + 3], (double)wgate_w[(k + 3) * 4 + e], a3);
    }
    g_lq[(size_t)qq * 4 + e] = (a0 + a1) + (a2 + a3);
  }
  __syncthreads();
  if (tid < 192) {
    double a0 = 0.0, a1 = 0.0, a2 = 0.0, a3 = 0.0;
    for (int k = 0; k < 64; k += 4) {
      a0 = fma(gi[k + 0], (double)gru_w_ih[tid * 64 + k + 0], a0);
      a1 = fma(gi[k + 1], (double)gru_w_ih[tid * 64 + k + 1], a1);
      a2 = fma(gi[k + 2], (double)gru_w_ih[tid * 64 + k + 2], a2);
      a3 = fma(gi[k + 3], (double)gru_w_ih[tid * 64 + k + 3], a3);
    }
    g_xgf[(size_t)qq * 192 + tid] = (float)((a0 + a1) + (a2 + a3));
  }
}

// ---------------------------------------------------------------------------
// gru: one wave per sequence, NO barriers.  64 blocks x 64 threads.
// Lane j owns h[j] (fp64 carry in reg) and computes full r/z/n dots for its j
// (fp32, W_hh rows in VGPRs, h broadcast via wave-private LDS mirror).
// x staged fp32 in LDS per GW-step chunk, pipelined one chunk ahead.
// ---------------------------------------------------------------------------
__global__ void __launch_bounds__(64, 1) gru_kernel(
    const int* __restrict__ q, const int* __restrict__ r,
    const float* __restrict__ whh, const float* __restrict__ bhh)
{
  __shared__ __align__(16) float XB[2][GW][192];
  __shared__ __align__(16) float HF[64];
  const int j = threadIdx.x;         // lane == thread
  const int b = blockIdx.x;

  // W_hh rows for this lane, fp32 in VGPRs (as float2 pairs)
  float2 Wr[32], Wz[32], Wn[32];
#pragma unroll
  for (int i = 0; i < 32; ++i) {
    Wr[i] = *(const float2*)(whh + (size_t)(0 * 64 + j) * 64 + 2 * i);
    Wz[i] = *(const float2*)(whh + (size_t)(1 * 64 + j) * 64 + 2 * i);
    Wn[i] = *(const float2*)(whh + (size_t)(2 * 64 + j) * 64 + 2 * i);
  }
  const double br = (double)bhh[j];
  const double bz = (double)bhh[64 + j];
  const double bn = (double)bhh[128 + j];
  const double xr0 = g_xgr[j],       xz0 = g_xgr[64 + j],       xn0 = g_xgr[128 + j];
  const double xr1 = g_xgr[192 + j], xz1 = g_xgr[256 + j],      xn1 = g_xgr[320 + j];

  // q/r lookahead registers (lane i < GW holds step s0+i of the chunk)
  int rv_cur = 0, qv_nxt = 0, rv_nxt = 0;
  if (j < GW) rv_cur = (j == 0) ? 2 : r[b * 512 + j - 1];
  {
    int qv0 = 0;
    if (j > 0 && j < GW) qv0 = q[b * 512 + j - 1];
#pragma unroll
    for (int s = 0; s < GW; ++s) {
      float v0, v1, v2;
      if (s == 0) {
        v0 = g_xg0f[j]; v1 = g_xg0f[64 + j]; v2 = g_xg0f[128 + j];
      } else {
        const int qo = __shfl(qv0, s);
        const size_t base = (size_t)qo * 192 + j;
        v0 = g_xgf[base]; v1 = g_xgf[base + 64]; v2 = g_xgf[base + 128];
      }
      XB[0][s][j] = v0; XB[0][s][64 + j] = v1; XB[0][s][128 + j] = v2;
    }
  }
  if (j < GW) {
    const int tk = GW + j - 1;
    qv_nxt = q[b * 512 + tk];
    rv_nxt = r[b * 512 + tk];
  }
  HF[j] = 0.f;
  double hd = 0.0;

  int p = 0;
  for (int cc = 0; cc < 512 / GW; ++cc) {
    // stage loads for chunk cc+1 (consumed by ds_write after the 8 steps)
    float xs0[GW], xs1[GW], xs2[GW];
    if (cc < 512 / GW - 1) {
#pragma unroll
      for (int s = 0; s < GW; ++s) {
        const int qo = __shfl(qv_nxt, s);
        const size_t base = (size_t)qo * 192 + j;
        xs0[s] = g_xgf[base];
        xs1[s] = g_xgf[base + 64];
        xs2[s] = g_xgf[base + 128];
      }
    }
    // q/r lookahead for chunk cc+2
    int qv_n2 = 0, rv_n2 = 0;
    if (cc < 512 / GW - 2 && j < GW) {
      const int tk = (cc + 2) * GW + j - 1;
      qv_n2 = q[b * 512 + tk];
      rv_n2 = r[b * 512 + tk];
    }

    const int sbase = cc * GW;
#pragma unroll
    for (int sc = 0; sc < GW; ++sc) {
      const int rs = __shfl(rv_cur, sc);
      const double xr = (double)XB[p][sc][j]
                      + ((rs == 0) ? xr0 : ((rs == 1) ? xr1 : 0.0));
      const double xz = (double)XB[p][sc][64 + j]
                      + ((rs == 0) ? xz0 : ((rs == 1) ? xz1 : 0.0));
      const double xn = (double)XB[p][sc][128 + j]
                      + ((rs == 0) ? xn0 : ((rs == 1) ? xn1 : 0.0));
      // broadcast-read h (conflict-free: all lanes same address)
      float2 h2[32];
      {
        const float4* hp = (const float4*)HF;
#pragma unroll
        for (int i = 0; i < 16; ++i) {
          const float4 t = hp[i];
          h2[2 * i]     = make_float2(t.x, t.y);
          h2[2 * i + 1] = make_float2(t.z, t.w);
        }
      }
      float arx = 0.f, ary = 0.f, azx = 0.f, azy = 0.f, anx = 0.f, any_ = 0.f;
#pragma unroll
      for (int i = 0; i < 32; ++i) {
        arx = fmaf(Wr[i].x, h2[i].x, arx); ary = fmaf(Wr[i].y, h2[i].y, ary);
        azx = fmaf(Wz[i].x, h2[i].x, azx); azy = fmaf(Wz[i].y, h2[i].y, azy);
        anx = fmaf(Wn[i].x, h2[i].x, anx); any_ = fmaf(Wn[i].y, h2[i].y, any_);
      }
      const double hr = br + (double)(arx + ary);
      const double hz = bz + (double)(azx + azy);
      const double hn = bn + (double)(anx + any_);
      const double pr = xr + hr, pz = xz + hz;
      double rg = fma(0.5, tpoly(0.5 * pr), 0.5);
      double zg = fma(0.5, tpoly(0.5 * pz), 0.5);
      double pre = fma(rg, hn, xn);
      double ng = tpoly(pre);
      const bool bad = (fabs(pr) > 0.5) | (fabs(pz) > 0.5) | (fabs(pre) > 0.25);
      if (bad) {   // rare slow path
        rg = 1.0 / (1.0 + fexp(-pr));
        zg = 1.0 / (1.0 + fexp(-pz));
        pre = fma(rg, hn, xn);
        ng = 1.0 - 2.0 / (fexp(pre + pre) + 1.0);
      }
      const double hnew = fma(zg, hd - ng, ng);   // (1-z)n + z h
      hd = hnew;
      const float hnf = (float)hnew;
      HF[j] = hnf;                                 // same-wave DS order
      g_m[((size_t)b * 512 + sbase + sc) * 64 + j] = hnf;
    }

    // publish staged x for chunk cc+1
    if (cc < 512 / GW - 1) {
#pragma unroll
      for (int s = 0; s < GW; ++s) {
        XB[p ^ 1][s][j] = xs0[s];
        XB[p ^ 1][s][64 + j] = xs1[s];
        XB[p ^ 1][s][128 + j] = xs2[s];
      }
    }
    rv_cur = rv_nxt;
    qv_nxt = qv_n2; rv_nxt = rv_n2;
    p ^= 1;
  }
}

// ---------------------------------------------------------------------------
// top1: logits = lq[q_t] + m_t @ wgate[256:320] + wgate_b ; first-max argmax.
// ---------------------------------------------------------------------------
__global__ void __launch_bounds__(256) top1_kernel(
    const int* __restrict__ q,
    const float* __restrict__ wgate_w, const float* __restrict__ wgate_b)
{
  __shared__ double w2[256];   // [j][e]
  const int tid = threadIdx.x;
  w2[tid] = (double)wgate_w[1024 + tid];
  __syncthreads();
  const int t = blockIdx.x * 256 + tid;
  const int qv = q[t];
  double l0 = g_lq[(size_t)qv * 4 + 0] + (double)wgate_b[0];
  double l1 = g_lq[(size_t)qv * 4 + 1] + (double)wgate_b[1];
  double l2 = g_lq[(size_t)qv * 4 + 2] + (double)wgate_b[2];
  double l3 = g_lq[(size_t)qv * 4 + 3] + (double)wgate_b[3];
  const float* mr = g_m + (size_t)t * 64;
  for (int jj = 0; jj < 64; ++jj) {
    const double mv = (double)mr[jj];
    l0 = fma(mv, w2[jj * 4 + 0], l0);
    l1 = fma(mv, w2[jj * 4 + 1], l1);
    l2 = fma(mv, w2[jj * 4 + 2], l2);
    l3 = fma(mv, w2[jj * 4 + 3], l3);
  }
  int bi = 0; double bvv = l0;
  if (l1 > bvv) { bvv = l1; bi = 1; }
  if (l2 > bvv) { bvv = l2; bi = 2; }
  if (l3 > bvv) { bvv = l3; bi = 3; }
  g_top1[t] = bi;
}

// ---------------------------------------------------------------------------
// kernelE: per 32 q-values: stage emb rows as bf16; for each expert e:
// h1=relu(qr_e@W1+b1) -> out=h1@W2+b2 -> LN -> qf[q][e] bf16.
// ---------------------------------------------------------------------------
__global__ void __launch_bounds__(128) kernelE(
    const float* __restrict__ emb,
    const float* __restrict__ b1, const float* __restrict__ b2,
    const float* __restrict__ lng, const float* __restrict__ lnb)
{
  __shared__ __align__(16) unsigned short QR[32 * 1032];
  __shared__ __align__(16) unsigned short H1[32 * 264];
  __shared__ __align__(16) unsigned short EO[32 * 264];
  const int tid = threadIdx.x;
  const int t0 = blockIdx.x * 32;
  const int w = tid >> 6;
  const int lane = tid & 63;
  const int l15 = lane & 15;
  const int quad = lane >> 4;

  for (int c = 0; c < 64; ++c) {
    const int idx = c * 128 + tid;
    const int row = idx >> 8, col4 = idx & 255;
    const int qv = min(t0 + row, NQ - 1);
    f32x4 v = *(const f32x4*)(emb + (size_t)qv * 1024 + col4 * 4);
    unsigned a = ((unsigned)f2bf(v[1]) << 16) | f2bf(v[0]);
    unsigned bb = ((unsigned)f2bf(v[3]) << 16) | f2bf(v[2]);
    *(uint2*)&QR[row * 1032 + col4 * 4] = make_uint2(a, bb);
  }
  __syncthreads();

  const f32x4 z4 = {0.f, 0.f, 0.f, 0.f};
  const int n0 = w * 128;

  for (int e = 0; e < 4; ++e) {
    f32x4 acc[2][8];
#pragma unroll
    for (int a = 0; a < 2; ++a)
#pragma unroll
      for (int bq = 0; bq < 8; ++bq) acc[a][bq] = z4;
#pragma unroll
    for (int ks = 0; ks < 8; ++ks) {
      const int koff = e * 256 + ks * 32 + quad * 8;
      bf16x8 a0 = *(const bf16x8*)&QR[l15 * 1032 + koff];
      bf16x8 a1 = *(const bf16x8*)&QR[(16 + l15) * 1032 + koff];
      const int kb = ks * 32 + quad * 8;
#pragma unroll
      for (int nt = 0; nt < 8; ++nt) {
        bf16x8 bbv = *(const bf16x8*)(g_w1t + (size_t)e * 65536 +
                                      (size_t)(n0 + nt * 16 + l15) * 256 + kb);
        acc[0][nt] = mfma16(a0, bbv, acc[0][nt]);
        acc[1][nt] = mfma16(a1, bbv, acc[1][nt]);
      }
    }
#pragma unroll
    for (int nt = 0; nt < 8; ++nt) {
      const int n = n0 + nt * 16 + l15;
      const float b1v = b1[e * 256 + n];
#pragma unroll
      for (int mt = 0; mt < 2; ++mt)
#pragma unroll
        for (int rg = 0; rg < 4; ++rg) {
          const int m = mt * 16 + quad * 4 + rg;
          H1[m * 264 + n] = f2bf(fmaxf(acc[mt][nt][rg] + b1v, 0.f));
        }
    }
    __syncthreads();
    f32x4 acc2[2][8];
#pragma unroll
    for (int a = 0; a < 2; ++a)
#pragma unroll
      for (int bq = 0; bq < 8; ++bq) acc2[a][bq] = z4;
#pragma unroll
    for (int ks = 0; ks < 8; ++ks) {
      const int koff = ks * 32 + quad * 8;
      bf16x8 a0 = *(const bf16x8*)&H1[l15 * 264 + koff];
      bf16x8 a1 = *(const bf16x8*)&H1[(16 + l15) * 264 + koff];
#pragma unroll
      for (int nt = 0; nt < 8; ++nt) {
        bf16x8 bbv = *(const bf16x8*)(g_w2t + (size_t)e * 65536 +
                                      (size_t)(n0 + nt * 16 + l15) * 256 + koff);
        acc2[0][nt] = mfma16(a0, bbv, acc2[0][nt]);
        acc2[1][nt] = mfma16(a1, bbv, acc2[1][nt]);
      }
    }
#pragma unroll
    for (int nt = 0; nt < 8; ++nt) {
      const int n = n0 + nt * 16 + l15;
      const float b2v = b2[e * 256 + n];
#pragma unroll
      for (int mt = 0; mt < 2; ++mt)
#pragma unroll
        for (int rg = 0; rg < 4; ++rg) {
          const int m = mt * 16 + quad * 4 + rg;
          EO[m * 264 + n] = f2bf(acc2[mt][nt][rg] + b2v);
        }
    }
    __syncthreads();
    {
      const int m = tid >> 2;
      const int sub = tid & 3;
      float sx = 0.f, sxx = 0.f;
#pragma unroll
      for (int i = 0; i < 8; ++i) {
        bf16x8 v = *(const bf16x8*)&EO[m * 264 + sub * 64 + i * 8];
#pragma unroll
        for (int c = 0; c < 8; ++c) {
          const float f = bf2f((unsigned short)v[c]);
          sx += f; sxx += f * f;
        }
      }
      sx += __shfl_xor(sx, 1); sxx += __shfl_xor(sxx, 1);
      sx += __shfl_xor(sx, 2); sxx += __shfl_xor(sxx, 2);
      const float mu = sx * (1.f / 256.f);
      const float var = sxx * (1.f / 256.f) - mu * mu;
      const float inv = 1.f / sqrtf(var + 1e-5f);
      if (t0 + m < NQ) {
        const size_t base = ((size_t)(t0 + m) * 4 + e) * 256;
#pragma unroll
        for (int i = 0; i < 8; ++i) {
          const int dbase = sub * 64 + i * 8;
          bf16x8 v = *(const bf16x8*)&EO[m * 264 + dbase];
          bf16x8 ov;
#pragma unroll
          for (int c = 0; c < 8; ++c) {
            const int d = dbase + c;
            const float f = bf2f((unsigned short)v[c]);
            ov[c] = (short)f2bf(lng[d] * (f - mu) * inv + lnb[d]);
          }
          *(bf16x8*)(g_qf + base + dbase) = ov;
        }
      }
    }
    __syncthreads();
  }
}

// ---------------------------------------------------------------------------
// kernelF: per 32 tokens: gather qf[q_t][top1_t] -> q_fused out (fp32) and
// LDS; proj (cor|inc) bf16 MFMA; qa_fused by r.
// ---------------------------------------------------------------------------
__global__ void __launch_bounds__(128) kernelF(
    const int* __restrict__ q, const int* __restrict__ r,
    const float* __restrict__ pcb, const float* __restrict__ pib,
    float* __restrict__ out)
{
  __shared__ __align__(16) unsigned short QF[32 * 264];
  __shared__ int rv_l[32];
  const int tid = threadIdx.x;
  const int t0 = blockIdx.x * 32;
  const int w = tid >> 6;
  const int lane = tid & 63;
  const int l15 = lane & 15;
  const int quad = lane >> 4;
  if (tid < 32) rv_l[tid] = r[t0 + tid];
  __syncthreads();

  {
    const int m = tid >> 2;
    const size_t row = ((size_t)q[t0 + m] * 4 + g_top1[t0 + m]) * 256;
#pragma unroll
    for (int i = 0; i < 8; ++i) {
      const int dbase = (tid & 3) * 64 + i * 8;
      bf16x8 v = *(const bf16x8*)(g_qf + row + dbase);
      *(bf16x8*)&QF[m * 264 + dbase] = v;
      f32x4 f0, f1;
#pragma unroll
      for (int c = 0; c < 4; ++c) f0[c] = bf2f((unsigned short)v[c]);
#pragma unroll
      for (int c = 0; c < 4; ++c) f1[c] = bf2f((unsigned short)v[4 + c]);
      *(f32x4*)(out + (size_t)(t0 + m) * 256 + dbase) = f0;
      *(f32x4*)(out + (size_t)(t0 + m) * 256 + dbase + 4) = f1;
    }
  }
  __syncthreads();

  const f32x4 z4 = {0.f, 0.f, 0.f, 0.f};
  const int n0 = w * 128;
  for (int ph = 0; ph < 2; ++ph) {
    f32x4 acc[2][8];
#pragma unroll
    for (int a = 0; a < 2; ++a)
#pragma unroll
      for (int bq = 0; bq < 8; ++bq) acc[a][bq] = z4;
#pragma unroll
    for (int ks = 0; ks < 8; ++ks) {
      const int koff = ks * 32 + quad * 8;
      bf16x8 a0 = *(const bf16x8*)&QF[l15 * 264 + koff];
      bf16x8 a1 = *(const bf16x8*)&QF[(16 + l15) * 264 + koff];
#pragma unroll
      for (int nt = 0; nt < 8; ++nt) {
        bf16x8 bbv = *(const bf16x8*)(g_projt +
            (size_t)(ph * 256 + n0 + nt * 16 + l15) * 256 + koff);
        acc[0][nt] = mfma16(a0, bbv, acc[0][nt]);
        acc[1][nt] = mfma16(a1, bbv, acc[1][nt]);
      }
    }
    const float* pbb = ph ? pib : pcb;
    const int want = ph ? 0 : 1;
#pragma unroll
    for (int nt = 0; nt < 8; ++nt) {
      const int n = n0 + nt * 16 + l15;
      const float pbv = pbb[n];
#pragma unroll
      for (int mt = 0; mt < 2; ++mt)
#pragma unroll
        for (int rg = 0; rg < 4; ++rg) {
          const int m = mt * 16 + quad * 4 + rg;
          if (rv_l[m] == want)
            out[(size_t)TT * 256 + (size_t)(t0 + m) * 256 + n] =
                acc[mt][nt][rg] + pbv;
        }
    }
  }
}

// ---------------------------------------------------------------------------
extern "C" void kernel_launch(void* const* d_in, const int* in_sizes, int n_in,
                              void* d_out, int out_size, void* d_ws, size_t ws_size,
                              hipStream_t stream)
{
  const int*   q   = (const int*)d_in[0];
  const int*   r   = (const int*)d_in[1];
  const float* emb = (const float*)d_in[2];
  const float* ew1 = (const float*)d_in[3];
  const float* eb1 = (const float*)d_in[4];
  const float* ew2 = (const float*)d_in[5];
  const float* eb2 = (const float*)d_in[6];
  const float* aw  = (const float*)d_in[7];
  const float* ab  = (const float*)d_in[8];
  const float* rw  = (const float*)d_in[9];
  const float* rb  = (const float*)d_in[10];
  const float* st  = (const float*)d_in[11];
  const float* wih = (const float*)d_in[12];
  const float* whh = (const float*)d_in[13];
  const float* bih = (const float*)d_in[14];
  const float* bhh = (const float*)d_in[15];
  const float* wgw = (const float*)d_in[16];
  const float* wgb = (const float*)d_in[17];
  const float* lng = (const float*)d_in[18];
  const float* lnb = (const float*)d_in[19];
  const float* resp= (const float*)d_in[20];
  const float* pcw = (const float*)d_in[21];
  const float* pcb = (const float*)d_in[22];
  const float* piw = (const float*)d_in[23];
  const float* pib = (const float*)d_in[24];
  float* out = (float*)d_out;
  (void)bih; (void)in_sizes; (void)n_in; (void)d_ws; (void)ws_size; (void)out_size;

  prep_kernel<<<64, 256, 0, stream>>>(ew1, ew2, pcw, piw, resp, rw, rb, st, wih, bih);
  qsk_kernel<<<dim3(157, 4), 256, 0, stream>>>(emb, aw, ab);
  smallk_kernel<<<NQ, 256, 0, stream>>>(rw, wih, wgw);
  gru_kernel<<<64, 64, 0, stream>>>(q, r, whh, bhh);
  top1_kernel<<<128, 256, 0, stream>>>(q, wgw, wgb);
  kernelE<<<313, 128, 0, stream>>>(emb, eb1, eb2, lng, lnb);
  kernelF<<<1024, 128, 0, stream>>>(q, r, pcb, pib, out);
}